// Round 6
// baseline (208.345 us; speedup 1.0000x reference)
//
#include <hip/hip_runtime.h>
#include <cstdint>

typedef unsigned short u16;
typedef __attribute__((ext_vector_type(8))) __bf16 bf16x8;
typedef __attribute__((ext_vector_type(4))) float f32x4;

#define NROWS 8192
#define KDIM  256
#define BM 128
#define BN 128
#define BK 64

__device__ __forceinline__ u16 f2bf(float f) {
  uint32_t u = __builtin_bit_cast(uint32_t, f);
  return (u16)((u + 0x7fffu + ((u >> 16) & 1u)) >> 16);
}

// One wave per row: convert f32 row (256 elems) to bf16 (RNE) and compute sum of squares.
__global__ void __launch_bounds__(256) prep_kernel(const float* __restrict__ src,
                                                   u16* __restrict__ dst,
                                                   float* __restrict__ norms) {
  const int row  = blockIdx.x * 4 + (threadIdx.x >> 6);
  const int lane = threadIdx.x & 63;
  const float4 v = *reinterpret_cast<const float4*>(&src[row * KDIM + lane * 4]);
  float s = v.x * v.x + v.y * v.y + v.z * v.z + v.w * v.w;
#pragma unroll
  for (int off = 32; off > 0; off >>= 1) s += __shfl_down(s, off, 64);
  ushort4 b;
  b.x = f2bf(v.x); b.y = f2bf(v.y); b.z = f2bf(v.z); b.w = f2bf(v.w);
  *reinterpret_cast<ushort4*>(&dst[row * KDIM + lane * 4]) = b;
  if (lane == 0) norms[row] = s;
}

// 128x128 tile, BK=64, 4 waves. K-loop identical to the proven 89.5us kernel
// (swapped-operand MFMA: acc=mfma(bfr,af) -> lane holds row=lane&15, cols=(lane>>4)*4+reg).
// NEW EPILOGUE: stage masked results through LDS (reusing sA/sB, dead after K-loop)
// so global stores are wave-contiguous full 128B lines (lane l -> col 4*(l&31) of one
// row; 2 rows x 512B per instruction). Partial-line scatters made L2 read-allocate
// each output line from HBM (~256MB of RFO reads); full-line writes skip it --
// evidence: harness fillBufferAligned writes 1GB at 6.9TB/s with FETCH_SIZE~0.
// SENTINEL: must not be -inf ((-inf)-(-inf)=NaN in the diff) and must stay finite
// under bf16 RNE (-FLT_MAX rounds to -inf in bf16); -3.0e38 is safe.
__global__ void __launch_bounds__(256) gemm_mask_kernel(const u16* __restrict__ A,
                                                        const u16* __restrict__ B,
                                                        const float* __restrict__ x2,
                                                        const float* __restrict__ y2,
                                                        float* __restrict__ out) {
  __shared__ __align__(16) u16 smem[16384];          // 32 KB
  u16* sA = smem;                                    // 128x64 bf16 (16 KB)
  u16* sB = smem + 8192;                             // 128x64 bf16 (16 KB)
  float* stg = reinterpret_cast<float*>(smem);       // epilogue: 64x128 f32 (32 KB)

  const int tid  = threadIdx.x;
  const int wave = tid >> 6;
  const int lane = tid & 63;
  const int lo = lane & 15, hi = lane >> 4;
  const int bx = blockIdx.x & 63;   // col tile
  const int by = blockIdx.x >> 6;   // row tile
  const int rowBase = by * BM;
  const int colBase = bx * BN;
  const int wr = wave >> 1;
  const int wc = wave & 1;

  f32x4 acc[4][4] = {};

  for (int k0 = 0; k0 < KDIM; k0 += BK) {
#pragma unroll
    for (int it = 0; it < 4; ++it) {
      const int e = it * 2048 + tid * 8;
      const int r = e >> 6;
      const int c = e & 63;
      const int ldsOff = it * 2048 + wave * 512;
      __builtin_amdgcn_global_load_lds(
          (const __attribute__((address_space(1))) void*)&A[(size_t)(rowBase + r) * KDIM + k0 + c],
          (__attribute__((address_space(3))) void*)&sA[ldsOff], 16, 0, 0);
      __builtin_amdgcn_global_load_lds(
          (const __attribute__((address_space(1))) void*)&B[(size_t)(colBase + r) * KDIM + k0 + c],
          (__attribute__((address_space(3))) void*)&sB[ldsOff], 16, 0, 0);
    }
    __syncthreads();

#pragma unroll
    for (int kk = 0; kk < BK; kk += 32) {
      const int kO = kk + hi * 8;
      bf16x8 af[4], bfr[4];
#pragma unroll
      for (int m = 0; m < 4; ++m)
        af[m] = *reinterpret_cast<const bf16x8*>(&sA[(wr * 64 + m * 16 + lo) * BK + kO]);
#pragma unroll
      for (int n = 0; n < 4; ++n)
        bfr[n] = *reinterpret_cast<const bf16x8*>(&sB[(wc * 64 + n * 16 + lo) * BK + kO]);
#pragma unroll
      for (int m = 0; m < 4; ++m)
#pragma unroll
        for (int n = 0; n < 4; ++n)
          acc[m][n] = __builtin_amdgcn_mfma_f32_16x16x32_bf16(bfr[n], af[m], acc[m][n], 0, 0, 0);
    }
    __syncthreads();   // also makes sA/sB safe to reuse after the last k0 iter
  }

  // ---- Epilogue: mask -> LDS staging -> full-line cooperative stores ----
  const float SENT = -3.0e38f;
  float4 yv[4];
#pragma unroll
  for (int n = 0; n < 4; ++n)
    yv[n] = *reinterpret_cast<const float4*>(&y2[colBase + wc * 64 + n * 16 + hi * 4]);
  float xr[4];
#pragma unroll
  for (int m = 0; m < 4; ++m) xr[m] = x2[rowBase + wr * 64 + m * 16 + lo];

#pragma unroll
  for (int h = 0; h < 2; ++h) {
    if (wr == h) {
      // This wave owns output rows [h*64, h*64+64). Write masked values into
      // stg[rl][c], 16B granules XOR-swizzled by (rl&31) for uniform banks.
#pragma unroll
      for (int m = 0; m < 4; ++m) {
        const int rl = m * 16 + lo;            // 0..63 local row
#pragma unroll
        for (int n = 0; n < 4; ++n) {
          float4 o;
          {
            float d2 = fmaxf(xr[m] + yv[n].x - 2.0f * acc[m][n][0], 0.0f);
            o.x = (d2 > 64.0f) ? SENT : -__builtin_sqrtf(d2);
          }
          {
            float d2 = fmaxf(xr[m] + yv[n].y - 2.0f * acc[m][n][1], 0.0f);
            o.y = (d2 > 64.0f) ? SENT : -__builtin_sqrtf(d2);
          }
          {
            float d2 = fmaxf(xr[m] + yv[n].z - 2.0f * acc[m][n][2], 0.0f);
            o.z = (d2 > 64.0f) ? SENT : -__builtin_sqrtf(d2);
          }
          {
            float d2 = fmaxf(xr[m] + yv[n].w - 2.0f * acc[m][n][3], 0.0f);
            o.w = (d2 > 64.0f) ? SENT : -__builtin_sqrtf(d2);
          }
          const int g = wc * 16 + n * 4 + hi;  // 16B granule within row, 0..31
          *reinterpret_cast<float4*>(&stg[(rl * 32 + (g ^ (rl & 31))) * 4]) = o;
        }
      }
    }
    __syncthreads();
    // Cooperative stores: lane l -> granule l&31 of row k*8 + wave*2 + (l>>5).
    // Per instruction: 2 rows x 512B contiguous = 8 full 128B lines.
    const int gcol = lane & 31;
    const int rsub = lane >> 5;
#pragma unroll
    for (int k = 0; k < 8; ++k) {
      const int r = k * 8 + wave * 2 + rsub;   // 0..63
      float4 v = *reinterpret_cast<const float4*>(&stg[(r * 32 + (gcol ^ (r & 31))) * 4]);
      *reinterpret_cast<float4*>(&out[(size_t)(rowBase + h * 64 + r) * NROWS + colBase + gcol * 4]) = v;
    }
    if (h == 0) __syncthreads();
  }
}

extern "C" void kernel_launch(void* const* d_in, const int* in_sizes, int n_in,
                              void* d_out, int out_size, void* d_ws, size_t ws_size,
                              hipStream_t stream) {
  const float* x  = (const float*)d_in[0];
  const float* xn = (const float*)d_in[1];
  float* out = (float*)d_out;

  // Workspace: bf16 X (4MB) | bf16 Xn (4MB) | x2 (32KB) | y2 (32KB)
  u16* Xb = (u16*)d_ws;
  u16* Yb = Xb + (size_t)NROWS * KDIM;
  float* x2 = (float*)(Yb + (size_t)NROWS * KDIM);
  float* y2 = x2 + NROWS;

  prep_kernel<<<NROWS / 4, 256, 0, stream>>>(x, Xb, x2);
  prep_kernel<<<NROWS / 4, 256, 0, stream>>>(xn, Yb, y2);
  gemm_mask_kernel<<<dim3(64 * 64), dim3(256), 0, stream>>>(Xb, Yb, x2, y2, out);
}

// Round 8
// 174.488 us; speedup vs baseline: 1.1940x; 1.1940x over previous
//
#include <hip/hip_runtime.h>
#include <cstdint>

typedef unsigned short u16;
typedef __attribute__((ext_vector_type(8))) __bf16 bf16x8;
typedef __attribute__((ext_vector_type(4))) float f32x4;

#define NROWS 8192
#define KDIM  256

__device__ __forceinline__ u16 f2bf(float f) {
  uint32_t u = __builtin_bit_cast(uint32_t, f);
  return (u16)((u + 0x7fffu + ((u >> 16) & 1u)) >> 16);
}

// One wave per row: convert f32 row (256 elems) to bf16 (RNE) and compute sum of squares.
__global__ void __launch_bounds__(256) prep_kernel(const float* __restrict__ src,
                                                   u16* __restrict__ dst,
                                                   float* __restrict__ norms) {
  const int row  = blockIdx.x * 4 + (threadIdx.x >> 6);
  const int lane = threadIdx.x & 63;
  const float4 v = *reinterpret_cast<const float4*>(&src[row * KDIM + lane * 4]);
  float s = v.x * v.x + v.y * v.y + v.z * v.z + v.w * v.w;
#pragma unroll
  for (int off = 32; off > 0; off >>= 1) s += __shfl_down(s, off, 64);
  ushort4 b;
  b.x = f2bf(v.x); b.y = f2bf(v.y); b.z = f2bf(v.z); b.w = f2bf(v.w);
  *reinterpret_cast<ushort4*>(&dst[row * KDIM + lane * 4]) = b;
  if (lane == 0) norms[row] = s;
}

// NO-LDS GEMM: inputs are 16MB total (L2/L3-resident) -> LDS staging is pure
// overhead (guide Common-mistake #7) and its barriers lockstep all waves
// (2-phase stall, m233). Each wave loads MFMA fragments straight from global
// (L1/L2), zero barriers, waves fully independent -> loads/MFMA/stores pipeline.
// Block = 128x128 tile, 4 waves each owning a 64x64 sub-tile (4x4 frags).
// SWAPPED-OPERAND MFMA: acc=mfma(bfr,af) => lane holds out row=lane&15,
// cols=(lane>>4)*4+reg -> float4 stores, consecutive n fill full 128B lines.
// XCD mapping: xcd=bid&7 owns col-tiles [xcd*8,xcd*8+8) -> 1MB B-panel stays in
// its private 4MB L2. Non-temporal stores (ext_vector f32x4 -- the builtin
// rejects HIP_vector_type float4) keep the 256MB out-stream from evicting A/B.
// SENTINEL: not -inf ((-inf)-(-inf)=NaN in harness diff) and finite under
// bf16 RNE (-FLT_MAX rounds to -inf); -3.0e38 is safe.
__global__ void __launch_bounds__(256) gemm_mask_kernel(const u16* __restrict__ A,
                                                        const u16* __restrict__ B,
                                                        const float* __restrict__ x2,
                                                        const float* __restrict__ y2,
                                                        float* __restrict__ out) {
  const int tid  = threadIdx.x;
  const int wave = tid >> 6;
  const int lane = tid & 63;
  const int lo = lane & 15, hi = lane >> 4;
  const int wr = wave >> 1, wc = wave & 1;

  const int xcd = blockIdx.x & 7;
  const int q   = blockIdx.x >> 3;        // 0..511
  const int bx  = xcd * 8 + (q & 7);      // col tile 0..63
  const int by  = q >> 3;                 // row tile 0..63
  const int rowBase = by * 128;
  const int colBase = bx * 128;

  // Per-wave row pointers (constant across ks).
  const u16* aRow[4];
  const u16* bRow[4];
#pragma unroll
  for (int m = 0; m < 4; ++m)
    aRow[m] = A + (size_t)(rowBase + wr * 64 + m * 16 + lo) * KDIM;
#pragma unroll
  for (int n = 0; n < 4; ++n)
    bRow[n] = B + (size_t)(colBase + wc * 64 + n * 16 + lo) * KDIM;

  f32x4 acc[4][4] = {};
#pragma unroll
  for (int ks = 0; ks < 8; ++ks) {
    const int kOff = ks * 32 + hi * 8;
    bf16x8 af[4], bfr[4];
#pragma unroll
    for (int m = 0; m < 4; ++m)
      af[m] = *reinterpret_cast<const bf16x8*>(&aRow[m][kOff]);
#pragma unroll
    for (int n = 0; n < 4; ++n)
      bfr[n] = *reinterpret_cast<const bf16x8*>(&bRow[n][kOff]);
#pragma unroll
    for (int m = 0; m < 4; ++m)
#pragma unroll
      for (int n = 0; n < 4; ++n)
        acc[m][n] = __builtin_amdgcn_mfma_f32_16x16x32_bf16(bfr[n], af[m], acc[m][n], 0, 0, 0);
  }

  // Fused epilogue: d2 = x2+y2-2*dot; out = d2>64 ? SENT : -sqrt(d2).
  const float SENT = -3.0e38f;
  float4 yv[4];
#pragma unroll
  for (int n = 0; n < 4; ++n)
    yv[n] = *reinterpret_cast<const float4*>(&y2[colBase + wc * 64 + n * 16 + hi * 4]);
#pragma unroll
  for (int m = 0; m < 4; ++m) {
    const int row  = rowBase + wr * 64 + m * 16 + lo;
    const float xr = x2[row];
    float* orow = out + (size_t)row * NROWS + colBase + wc * 64 + hi * 4;
#pragma unroll
    for (int n = 0; n < 4; ++n) {
      f32x4 o;
      {
        float d2 = fmaxf(xr + yv[n].x - 2.0f * acc[m][n][0], 0.0f);
        o[0] = (d2 > 64.0f) ? SENT : -__builtin_sqrtf(d2);
      }
      {
        float d2 = fmaxf(xr + yv[n].y - 2.0f * acc[m][n][1], 0.0f);
        o[1] = (d2 > 64.0f) ? SENT : -__builtin_sqrtf(d2);
      }
      {
        float d2 = fmaxf(xr + yv[n].z - 2.0f * acc[m][n][2], 0.0f);
        o[2] = (d2 > 64.0f) ? SENT : -__builtin_sqrtf(d2);
      }
      {
        float d2 = fmaxf(xr + yv[n].w - 2.0f * acc[m][n][3], 0.0f);
        o[3] = (d2 > 64.0f) ? SENT : -__builtin_sqrtf(d2);
      }
      __builtin_nontemporal_store(o, reinterpret_cast<f32x4*>(&orow[n * 16]));
    }
  }
}

extern "C" void kernel_launch(void* const* d_in, const int* in_sizes, int n_in,
                              void* d_out, int out_size, void* d_ws, size_t ws_size,
                              hipStream_t stream) {
  const float* x  = (const float*)d_in[0];
  const float* xn = (const float*)d_in[1];
  float* out = (float*)d_out;

  // Workspace: bf16 X (4MB) | bf16 Xn (4MB) | x2 (32KB) | y2 (32KB)
  u16* Xb = (u16*)d_ws;
  u16* Yb = Xb + (size_t)NROWS * KDIM;
  float* x2 = (float*)(Yb + (size_t)NROWS * KDIM);
  float* y2 = x2 + NROWS;

  prep_kernel<<<NROWS / 4, 256, 0, stream>>>(x, Xb, x2);
  prep_kernel<<<NROWS / 4, 256, 0, stream>>>(xn, Yb, y2);
  gemm_mask_kernel<<<dim3(64 * 64), dim3(256), 0, stream>>>(Xb, Yb, x2, y2, out);
}

// Round 9
// 119.653 us; speedup vs baseline: 1.7413x; 1.4583x over previous
//
#include <hip/hip_runtime.h>
#include <cstdint>

typedef unsigned short u16;
typedef __attribute__((ext_vector_type(8))) __bf16 bf16x8;
typedef __attribute__((ext_vector_type(4))) float f32x4;

#define NROWS 8192
#define KDIM  256

__device__ __forceinline__ u16 f2bf(float f) {
  uint32_t u = __builtin_bit_cast(uint32_t, f);
  return (u16)((u + 0x7fffu + ((u >> 16) & 1u)) >> 16);
}

// One wave per row: convert f32 row (256 elems) to bf16 (RNE) and compute sum of squares.
__global__ void __launch_bounds__(256) prep_kernel(const float* __restrict__ src,
                                                   u16* __restrict__ dst,
                                                   float* __restrict__ norms) {
  const int row  = blockIdx.x * 4 + (threadIdx.x >> 6);
  const int lane = threadIdx.x & 63;
  const float4 v = *reinterpret_cast<const float4*>(&src[row * KDIM + lane * 4]);
  float s = v.x * v.x + v.y * v.y + v.z * v.z + v.w * v.w;
#pragma unroll
  for (int off = 32; off > 0; off >>= 1) s += __shfl_down(s, off, 64);
  ushort4 b;
  b.x = f2bf(v.x); b.y = f2bf(v.y); b.z = f2bf(v.z); b.w = f2bf(v.w);
  *reinterpret_cast<ushort4*>(&dst[row * KDIM + lane * 4]) = b;
  if (lane == 0) norms[row] = s;
}

// 256x256 tile, BK=32 (8 K-tiles), 8 waves (2Mx4N), 512 threads.
// TRIPLE-BUFFERED LDS (3 x 32KB): tile t+2 staged during tile t, so the tile
// boundary waits s_waitcnt vmcnt(4) -- counted, never drain-to-0 (T3+T4).
// Raw s_barrier (asm, no implicit vmcnt drain) + setprio(1) around MFMA (T5).
// LDS layout per buffer: A[chunk(4)][row(256)][8 bf16] then B same at +8192
// elems; ds_read_b128 start-bank = (row&7)*4 -> exactly 8 lanes/bank-group =
// conflict-free. gload_lds dest = uniform base + tid*16 (linear) with per-lane
// global source (rule 21): cell c = chunk*256+row staged by thread c%512,
// round c/512.
// SWAPPED-OPERAND MFMA (verified r4): acc=mfma(bf,af) => out row = lane&15,
// out cols = (lane>>4)*4+reg -> float4 epilogue stores. NO nontemporal stores
// (r8: NT amplified WRITE_SIZE +30%). SENTINEL: not -inf ((-inf)-(-inf)=NaN in
// harness diff) and finite under bf16 RNE (-FLT_MAX rounds to -inf in bf16).
__global__ void __launch_bounds__(512, 2) gemm_mask_kernel(const u16* __restrict__ A,
                                                           const u16* __restrict__ B,
                                                           const float* __restrict__ x2,
                                                           const float* __restrict__ y2,
                                                           float* __restrict__ out) {
  extern __shared__ __align__(16) u16 smem[];   // 3 * 16384 elems = 96 KB
  const int tid  = threadIdx.x;
  const int wave = tid >> 6;
  const int lane = tid & 63;
  const int lo = lane & 15, hi = lane >> 4;
  const int wr = wave >> 2, wc = wave & 3;      // 2 x 4 wave grid

  // XCD-bijective mapping: 1024 blocks, 128/XCD; bx slow, by fast ->
  // each XCD keeps its 4 B-panels (512 KB) L2-resident.
  const int swz = (blockIdx.x & 7) * 128 + (blockIdx.x >> 3);
  const int bx = swz >> 5, by = swz & 31;
  const int rowBase = by * 256, colBase = bx * 256;

  // Per-thread staging source bases: cell c = chunk*256+row; thread stages
  // c = j*512 + tid  ->  row = tid&255, chunk = j*2 + (tid>>8).
  const u16* baseA = A + (size_t)(rowBase + (tid & 255)) * KDIM + (tid >> 8) * 8;
  const u16* baseB = B + (size_t)(colBase + (tid & 255)) * KDIM + (tid >> 8) * 8;

  // ds_read bases (elems within buffer): chunk = hi.
  const int rdA = (hi * 256 + wr * 128 + lo) * 8;
  const int rdB = 8192 + (hi * 256 + wc * 64 + lo) * 8;

  f32x4 acc[8][4] = {};

  // Stage round j of half (0=A,1=B) of K-tile s: 16B/thread.
#define STG(s, half, j)                                                                   \
  __builtin_amdgcn_global_load_lds(                                                       \
      (const __attribute__((address_space(1))) void*)(((half) ? baseB : baseA) + (s) * 32 + (j) * 16), \
      (__attribute__((address_space(3))) void*)(smem + ((s) % 3) * 16384 + (half) * 8192 + (j) * 4096 + tid * 8), \
      16, 0, 0)

  // Prologue: stage tiles 0 and 1 (8 loads/thread); wait tile0 (leave tile1 flying).
  STG(0, 0, 0); STG(0, 0, 1); STG(0, 1, 0); STG(0, 1, 1);
  STG(1, 0, 0); STG(1, 0, 1); STG(1, 1, 0); STG(1, 1, 1);
  asm volatile("s_waitcnt vmcnt(4)" ::: "memory");
  asm volatile("s_barrier" ::: "memory");

#pragma unroll
  for (int t = 0; t < 8; ++t) {
    const u16* sa = smem + (t % 3) * 16384;
    bf16x8 bf[4];
#pragma unroll
    for (int mh = 0; mh < 2; ++mh) {
      // Issue stage of tile t+2 (buffer (t+2)%3 == (t-1)%3, reads done at end of t-1).
      if (t + 2 < 8) {
        if (mh == 0) { STG(t + 2, 0, 0); STG(t + 2, 0, 1); }
        else         { STG(t + 2, 1, 0); STG(t + 2, 1, 1); }
      }
      // ds_read this phase's fragments (latency hides under the barrier).
      bf16x8 af[4];
#pragma unroll
      for (int m = 0; m < 4; ++m)
        af[m] = *reinterpret_cast<const bf16x8*>(sa + rdA + mh * 512 + m * 128);
      if (mh == 0) {
#pragma unroll
        for (int n = 0; n < 4; ++n)
          bf[n] = *reinterpret_cast<const bf16x8*>(sa + rdB + n * 128);
      }
      asm volatile("s_barrier" ::: "memory");
      __builtin_amdgcn_sched_barrier(0);
      __builtin_amdgcn_s_setprio(1);
#pragma unroll
      for (int m = 0; m < 4; ++m)
#pragma unroll
        for (int n = 0; n < 4; ++n)
          acc[mh * 4 + m][n] =
              __builtin_amdgcn_mfma_f32_16x16x32_bf16(bf[n], af[m], acc[mh * 4 + m][n], 0, 0, 0);
      __builtin_amdgcn_s_setprio(0);
      if (mh == 1) {
        if (t < 6)       asm volatile("s_waitcnt vmcnt(4)" ::: "memory");  // tile t+1 landed
        else if (t == 6) asm volatile("s_waitcnt vmcnt(0)" ::: "memory");  // tile 7 landed
      }
      asm volatile("s_barrier" ::: "memory");
    }
  }
#undef STG

  // Fused epilogue: d2 = x2+y2-2*dot; out = d2>64 ? SENT : -sqrt(d2). float4 stores.
  const float SENT = -3.0e38f;
  float4 yv[4];
#pragma unroll
  for (int n = 0; n < 4; ++n)
    yv[n] = *reinterpret_cast<const float4*>(&y2[colBase + wc * 64 + n * 16 + hi * 4]);
#pragma unroll
  for (int m = 0; m < 8; ++m) {
    const int row  = rowBase + wr * 128 + m * 16 + lo;
    const float xr = x2[row];
    float* orow = out + (size_t)row * NROWS + colBase + wc * 64 + hi * 4;
#pragma unroll
    for (int n = 0; n < 4; ++n) {
      float4 o;
      {
        float d2 = fmaxf(xr + yv[n].x - 2.0f * acc[m][n][0], 0.0f);
        o.x = (d2 > 64.0f) ? SENT : -__builtin_sqrtf(d2);
      }
      {
        float d2 = fmaxf(xr + yv[n].y - 2.0f * acc[m][n][1], 0.0f);
        o.y = (d2 > 64.0f) ? SENT : -__builtin_sqrtf(d2);
      }
      {
        float d2 = fmaxf(xr + yv[n].z - 2.0f * acc[m][n][2], 0.0f);
        o.z = (d2 > 64.0f) ? SENT : -__builtin_sqrtf(d2);
      }
      {
        float d2 = fmaxf(xr + yv[n].w - 2.0f * acc[m][n][3], 0.0f);
        o.w = (d2 > 64.0f) ? SENT : -__builtin_sqrtf(d2);
      }
      *reinterpret_cast<float4*>(&orow[n * 16]) = o;
    }
  }
}

extern "C" void kernel_launch(void* const* d_in, const int* in_sizes, int n_in,
                              void* d_out, int out_size, void* d_ws, size_t ws_size,
                              hipStream_t stream) {
  const float* x  = (const float*)d_in[0];
  const float* xn = (const float*)d_in[1];
  float* out = (float*)d_out;

  // Workspace: bf16 X (4MB) | bf16 Xn (4MB) | x2 (32KB) | y2 (32KB)
  u16* Xb = (u16*)d_ws;
  u16* Yb = Xb + (size_t)NROWS * KDIM;
  float* x2 = (float*)(Yb + (size_t)NROWS * KDIM);
  float* y2 = x2 + NROWS;

  prep_kernel<<<NROWS / 4, 256, 0, stream>>>(x, Xb, x2);
  prep_kernel<<<NROWS / 4, 256, 0, stream>>>(xn, Yb, y2);
  gemm_mask_kernel<<<dim3(1024), dim3(512), 98304, stream>>>(Xb, Yb, x2, y2, out);
}

// Round 10
// 109.828 us; speedup vs baseline: 1.8970x; 1.0895x over previous
//
#include <hip/hip_runtime.h>
#include <cstdint>

typedef unsigned short u16;
typedef __attribute__((ext_vector_type(8))) __bf16 bf16x8;
typedef __attribute__((ext_vector_type(4))) float f32x4;

#define NROWS 8192
#define KDIM  256

__device__ __forceinline__ u16 f2bf(float f) {
  uint32_t u = __builtin_bit_cast(uint32_t, f);
  return (u16)((u + 0x7fffu + ((u >> 16) & 1u)) >> 16);
}

// One wave per row: convert f32 row (256 elems) to bf16 (RNE) and compute sum of squares.
__global__ void __launch_bounds__(256) prep_kernel(const float* __restrict__ src,
                                                   u16* __restrict__ dst,
                                                   float* __restrict__ norms) {
  const int row  = blockIdx.x * 4 + (threadIdx.x >> 6);
  const int lane = threadIdx.x & 63;
  const float4 v = *reinterpret_cast<const float4*>(&src[row * KDIM + lane * 4]);
  float s = v.x * v.x + v.y * v.y + v.z * v.z + v.w * v.w;
#pragma unroll
  for (int off = 32; off > 0; off >>= 1) s += __shfl_down(s, off, 64);
  ushort4 b;
  b.x = f2bf(v.x); b.y = f2bf(v.y); b.z = f2bf(v.z); b.w = f2bf(v.w);
  *reinterpret_cast<ushort4*>(&dst[row * KDIM + lane * 4]) = b;
  if (lane == 0) norms[row] = s;
}

// Round-4 kernel (proven 89.5us) with ONE structural change: the K-loop's
// __syncthreads (which drains vmcnt to 0, serializing stage(t) vs compute(t-1))
// is replaced by BK=32 DOUBLE-BUFFERING (same 32KB LDS) + raw s_barrier +
// COUNTED s_waitcnt vmcnt(4) (T3/T4): tile t+1 stays in flight under compute(t).
// LDS cells [chunk(4)][row(128)][8 bf16]: linear dest (tid*16B) with per-lane
// pre-computed source (rule 21); ds_read_b128 over 16 consecutive rows spans
// all 32 banks (2-way aliasing = free, m136). 4 waves (2x2), 64x64/wave.
// SWAPPED-OPERAND MFMA (verified r4): acc=mfma(bf,af) => out row=lane&15,
// cols=(lane>>4)*4+reg -> float4 stores. Plain cached stores (r8: NT = +30%
// WRITE_SIZE). XCD-bijective swizzle (verified r8): xcd=bid&7 owns 8 col
// panels -> 512KB B L2-resident/XCD. SENTINEL: not -inf ((-inf)-(-inf)=NaN in
// harness diff) and finite under bf16 RNE (-FLT_MAX bf16-rounds to -inf).
__global__ void __launch_bounds__(256) gemm_mask_kernel(const u16* __restrict__ A,
                                                        const u16* __restrict__ B,
                                                        const float* __restrict__ x2,
                                                        const float* __restrict__ y2,
                                                        float* __restrict__ out) {
  __shared__ __align__(16) u16 smem[16384];   // 2 buffers x (A 4096 + B 4096 elems) = 32 KB
  const int tid  = threadIdx.x;
  const int wave = tid >> 6;
  const int lane = tid & 63;
  const int lo = lane & 15, hi = lane >> 4;
  const int wr = wave >> 1, wc = wave & 1;

  const int xcd = blockIdx.x & 7;
  const int i   = blockIdx.x >> 3;        // 0..511
  const int bx  = xcd * 8 + (i & 7);      // col tile 0..63
  const int by  = i >> 3;                 // row tile 0..63
  const int rowBase = by * 128;
  const int colBase = bx * 128;

  // Staging: cell c=(chunk*128+row), thread stages cells tid and tid+256.
  // src k-offset = chunk*8; dest = linear tid*8 elems (16B/thread).
  const u16* srcA = A + (size_t)(rowBase + (tid & 127)) * KDIM + (tid >> 7) * 8;
  const u16* srcB = B + (size_t)(colBase + (tid & 127)) * KDIM + (tid >> 7) * 8;

#define STG(s, buf)                                                                        \
  do {                                                                                     \
    __builtin_amdgcn_global_load_lds(                                                      \
        (const __attribute__((address_space(1))) void*)(srcA + (s) * 32),                  \
        (__attribute__((address_space(3))) void*)(smem + (buf) * 8192 + tid * 8), 16, 0, 0); \
    __builtin_amdgcn_global_load_lds(                                                      \
        (const __attribute__((address_space(1))) void*)(srcA + (s) * 32 + 16),             \
        (__attribute__((address_space(3))) void*)(smem + (buf) * 8192 + tid * 8 + 2048), 16, 0, 0); \
    __builtin_amdgcn_global_load_lds(                                                      \
        (const __attribute__((address_space(1))) void*)(srcB + (s) * 32),                  \
        (__attribute__((address_space(3))) void*)(smem + (buf) * 8192 + 4096 + tid * 8), 16, 0, 0); \
    __builtin_amdgcn_global_load_lds(                                                      \
        (const __attribute__((address_space(1))) void*)(srcB + (s) * 32 + 16),             \
        (__attribute__((address_space(3))) void*)(smem + (buf) * 8192 + 4096 + tid * 8 + 2048), 16, 0, 0); \
  } while (0)

  f32x4 acc[4][4] = {};

  // Prologue: tiles 0,1 in flight; wait tile 0 only (tile 1 stays flying).
  STG(0, 0);
  STG(1, 1);
  asm volatile("s_waitcnt vmcnt(4)" ::: "memory");
  asm volatile("s_barrier" ::: "memory");

#pragma unroll
  for (int t = 0; t < 8; ++t) {
    const u16* sa = smem + (t & 1) * 8192;
    bf16x8 af[4], bf[4];
#pragma unroll
    for (int m = 0; m < 4; ++m)
      af[m] = *reinterpret_cast<const bf16x8*>(sa + (hi * 128 + wr * 64 + m * 16 + lo) * 8);
#pragma unroll
    for (int n = 0; n < 4; ++n)
      bf[n] = *reinterpret_cast<const bf16x8*>(sa + 4096 + (hi * 128 + wc * 64 + n * 16 + lo) * 8);
    __builtin_amdgcn_s_setprio(1);
#pragma unroll
    for (int m = 0; m < 4; ++m)
#pragma unroll
      for (int n = 0; n < 4; ++n)
        acc[m][n] = __builtin_amdgcn_mfma_f32_16x16x32_bf16(bf[n], af[m], acc[m][n], 0, 0, 0);
    __builtin_amdgcn_s_setprio(0);
    if (t < 7) {
      asm volatile("s_barrier" ::: "memory");           // block done reading buf[t&1]
      if (t + 2 < 8) {
        STG(t + 2, t & 1);                              // refill dead buffer
        asm volatile("s_waitcnt vmcnt(4)" ::: "memory"); // tile t+1 landed (t+2 in flight)
      } else {
        asm volatile("s_waitcnt vmcnt(0)" ::: "memory"); // tile 7 landed
      }
      asm volatile("s_barrier" ::: "memory");           // tile t+1 visible block-wide
    }
  }
#undef STG

  // Fused epilogue (r4-proven): d2 = x2+y2-2*dot; out = d2>64 ? SENT : -sqrt(d2).
  const float SENT = -3.0e38f;
  float4 yv[4];
#pragma unroll
  for (int n = 0; n < 4; ++n)
    yv[n] = *reinterpret_cast<const float4*>(&y2[colBase + wc * 64 + n * 16 + hi * 4]);
#pragma unroll
  for (int m = 0; m < 4; ++m) {
    const int row  = rowBase + wr * 64 + m * 16 + lo;
    const float xr = x2[row];
    float* orow = out + (size_t)row * NROWS + colBase + wc * 64 + hi * 4;
#pragma unroll
    for (int n = 0; n < 4; ++n) {
      float4 o;
      {
        float d2 = fmaxf(xr + yv[n].x - 2.0f * acc[m][n][0], 0.0f);
        o.x = (d2 > 64.0f) ? SENT : -__builtin_sqrtf(d2);
      }
      {
        float d2 = fmaxf(xr + yv[n].y - 2.0f * acc[m][n][1], 0.0f);
        o.y = (d2 > 64.0f) ? SENT : -__builtin_sqrtf(d2);
      }
      {
        float d2 = fmaxf(xr + yv[n].z - 2.0f * acc[m][n][2], 0.0f);
        o.z = (d2 > 64.0f) ? SENT : -__builtin_sqrtf(d2);
      }
      {
        float d2 = fmaxf(xr + yv[n].w - 2.0f * acc[m][n][3], 0.0f);
        o.w = (d2 > 64.0f) ? SENT : -__builtin_sqrtf(d2);
      }
      *reinterpret_cast<float4*>(&orow[n * 16]) = o;
    }
  }
}

extern "C" void kernel_launch(void* const* d_in, const int* in_sizes, int n_in,
                              void* d_out, int out_size, void* d_ws, size_t ws_size,
                              hipStream_t stream) {
  const float* x  = (const float*)d_in[0];
  const float* xn = (const float*)d_in[1];
  float* out = (float*)d_out;

  // Workspace: bf16 X (4MB) | bf16 Xn (4MB) | x2 (32KB) | y2 (32KB)
  u16* Xb = (u16*)d_ws;
  u16* Yb = Xb + (size_t)NROWS * KDIM;
  float* x2 = (float*)(Yb + (size_t)NROWS * KDIM);
  float* y2 = x2 + NROWS;

  prep_kernel<<<NROWS / 4, 256, 0, stream>>>(x, Xb, x2);
  prep_kernel<<<NROWS / 4, 256, 0, stream>>>(xn, Yb, y2);
  gemm_mask_kernel<<<dim3(64 * 64), dim3(256), 0, stream>>>(Xb, Yb, x2, y2, out);
}